// Round 7
// baseline (130.809 us; speedup 1.0000x reference)
//
#include <hip/hip_runtime.h>
#include <hip/hip_bf16.h>
#include <math.h>

#define BB 16
#define NN 8192
#define DD 768
#define HH 3072
#define EPSV 1e-6f
#define DSQRT 0.03608439182435161f   // 768^-0.5

#define CHUNKS 64
#define ROWS_PER_BLOCK (NN / CHUNKS)              // 128
#define NWAVES 4
#define ROWS_PER_WAVE (ROWS_PER_BLOCK / NWAVES)   // 32
#define PSTRIDE 772                               // 768 pooled + 1 denom
#define QQ 4                                      // chunk quarters

#define KS1 16
#define KL1 (DD / KS1)    // 48
#define KS2 48
#define KL2 (HH / KS2)    // 64

// ---------------------------------------------------------------------------
// Kernel A (byte-identical to R3/R6 best): single pass over x.
// ---------------------------------------------------------------------------
__global__ __launch_bounds__(256) void attn_pool_k(
    const float* __restrict__ x, const float* __restrict__ query,
    float* __restrict__ attn_out, float* __restrict__ partials)
{
    const int b     = blockIdx.y;
    const int chunk = blockIdx.x;
    const int tid   = threadIdx.x;
    const int wave  = tid >> 6;
    const int lane  = tid & 63;

    const float4* q4 = (const float4*)query;
    const float4 q0 = q4[lane];
    const float4 q1 = q4[lane + 64];
    const float4 q2 = q4[lane + 128];

    float4 p0 = make_float4(0.f, 0.f, 0.f, 0.f);
    float4 p1 = make_float4(0.f, 0.f, 0.f, 0.f);
    float4 p2 = make_float4(0.f, 0.f, 0.f, 0.f);
    float esum = 0.f;

    const int n0 = chunk * ROWS_PER_BLOCK + wave * ROWS_PER_WAVE;
    const float4* xb = (const float4*)(x + (size_t)b * NN * DD);

    #pragma unroll 2
    for (int r = 0; r < ROWS_PER_WAVE; ++r) {
        const int n = n0 + r;
        const float4* xr = xb + (size_t)n * (DD / 4);
        const float4 v0 = xr[lane];
        const float4 v1 = xr[lane + 64];
        const float4 v2 = xr[lane + 128];

        float s = v0.x * q0.x + v0.y * q0.y + v0.z * q0.z + v0.w * q0.w;
        s += v1.x * q1.x + v1.y * q1.y + v1.z * q1.z + v1.w * q1.w;
        s += v2.x * q2.x + v2.y * q2.y + v2.z * q2.z + v2.w * q2.w;
        #pragma unroll
        for (int off = 32; off > 0; off >>= 1) s += __shfl_xor(s, off);

        if (lane == 0) attn_out[(size_t)b * NN + n] = s;  // raw logit

        const float e = expf(s * DSQRT);
        esum += e;
        p0.x += e * v0.x; p0.y += e * v0.y; p0.z += e * v0.z; p0.w += e * v0.w;
        p1.x += e * v1.x; p1.y += e * v1.y; p1.z += e * v1.z; p1.w += e * v1.w;
        p2.x += e * v2.x; p2.y += e * v2.y; p2.z += e * v2.z; p2.w += e * v2.w;
    }

    __shared__ float lds[NWAVES][PSTRIDE];
    float* my = lds[wave];
    *(float4*)&my[lane * 4]       = p0;
    *(float4*)&my[256 + lane * 4] = p1;
    *(float4*)&my[512 + lane * 4] = p2;
    if (lane == 0) my[768] = esum;
    __syncthreads();

    float* outp = partials + (size_t)(b * CHUNKS + chunk) * PSTRIDE;
    #pragma unroll
    for (int k = 0; k < 3; ++k) {
        const int idx = tid + k * 256;
        outp[idx] = lds[0][idx] + lds[1][idx] + lds[2][idx] + lds[3][idx];
    }
    if (tid == 0) outp[768] = lds[0][768] + lds[1][768] + lds[2][768] + lds[3][768];
}

// ---------------------------------------------------------------------------
// Kernel B: quarter-reduce of partials (192 blocks), then the LAST block to
// finish performs all 16 LayerNorms wave-parallel (shuffle-only, no
// syncthreads). Release: threadfence + atomicAdd; acquire: fence after RMW.
// Value-deterministic: fixed-order arithmetic regardless of which block runs.
// ---------------------------------------------------------------------------
__global__ __launch_bounds__(256) void qreduce_ln_k(
    const float* __restrict__ partials, float* __restrict__ qsum,
    float* __restrict__ qden, const float* __restrict__ gamma,
    const float* __restrict__ beta, float* __restrict__ pooled,
    float* __restrict__ hln, int* __restrict__ qcnt)
{
    const int slice = blockIdx.x % 3;
    const int q     = blockIdx.x / 3;
    const int b0    = blockIdx.y;
    const int tid   = threadIdx.x;
    const float* pb = partials + (size_t)b0 * CHUNKS * PSTRIDE;

    const int col0 = slice * 256 + tid;
    float s = 0.f;
    #pragma unroll
    for (int c = 0; c < CHUNKS / QQ; ++c)
        s += pb[(q * (CHUNKS / QQ) + c) * PSTRIDE + col0];
    qsum[(size_t)(b0 * QQ + q) * DD + col0] = s;

    if (slice == 0 && tid < CHUNKS / QQ) {   // 16 lanes, parallel denom reduce
        float dn = pb[(q * (CHUNKS / QQ) + tid) * PSTRIDE + 768];
        #pragma unroll
        for (int off = 8; off > 0; off >>= 1) dn += __shfl_xor(dn, off, 16);
        if (tid == 0) qden[b0 * QQ + q] = dn;
    }

    // ---- last-block LN ----
    __threadfence();
    __shared__ int s_last;
    if (tid == 0) s_last = (atomicAdd(qcnt, 1) == 12 * BB - 1) ? 1 : 0;
    __syncthreads();
    if (!s_last) return;
    __threadfence();

    const int wave = tid >> 6, lane = tid & 63;
    for (int b = wave; b < BB; b += 4) {
        const float den = qden[b * QQ] + qden[b * QQ + 1]
                        + qden[b * QQ + 2] + qden[b * QQ + 3];
        const float inv = 1.f / den;
        float v[12];
        float sum = 0.f;
        #pragma unroll
        for (int c = 0; c < 12; ++c) {
            const int col = c * 64 + lane;
            float t = qsum[(size_t)(b * QQ + 0) * DD + col]
                    + qsum[(size_t)(b * QQ + 1) * DD + col]
                    + qsum[(size_t)(b * QQ + 2) * DD + col]
                    + qsum[(size_t)(b * QQ + 3) * DD + col];
            v[c] = t * inv;
            sum += v[c];
        }
        #pragma unroll
        for (int off = 32; off > 0; off >>= 1) sum += __shfl_xor(sum, off);
        const float mu = sum * (1.f / 768.f);
        float sq = 0.f;
        #pragma unroll
        for (int c = 0; c < 12; ++c) { const float d = v[c] - mu; sq += d * d; }
        #pragma unroll
        for (int off = 32; off > 0; off >>= 1) sq += __shfl_xor(sq, off);
        const float rstd = rsqrtf(sq * (1.f / 768.f) + EPSV);
        #pragma unroll
        for (int c = 0; c < 12; ++c) {
            const int col = c * 64 + lane;
            pooled[(size_t)b * DD + col] = v[c];
            hln[(size_t)b * DD + col] = (v[c] - mu) * rstd * gamma[col] + beta[col];
        }
    }
    __syncthreads();
    if (tid == 0) *qcnt = 0;   // reset for next replay
}

// ---------------------------------------------------------------------------
// Kernel C: B-major K-split partial of hln @ w1. grid (12, 16) = 192 blocks.
// ---------------------------------------------------------------------------
__global__ __launch_bounds__(256) void gemm1_part_k(
    const float* __restrict__ hln_ws, const float* __restrict__ w1,
    float* __restrict__ g1p)
{
    const int j  = blockIdx.x * 256 + threadIdx.x;  // hidden column
    const int k0 = blockIdx.y * KL1;                // K offset

    __shared__ float hl[BB][KL1];
    for (int i = threadIdx.x; i < BB * KL1; i += 256) {
        const int b = i / KL1, d = i - b * KL1;
        hl[b][d] = hln_ws[(size_t)b * DD + k0 + d];
    }
    __syncthreads();

    float wv[KL1];
    #pragma unroll
    for (int d = 0; d < KL1; ++d) wv[d] = w1[(size_t)(k0 + d) * HH + j];

    float acc[BB];
    #pragma unroll
    for (int b = 0; b < BB; ++b) acc[b] = 0.f;

    #pragma unroll
    for (int d4 = 0; d4 < KL1 / 4; ++d4) {
        #pragma unroll
        for (int b = 0; b < BB; ++b) {
            const float4 h4 = *(const float4*)&hl[b][d4 * 4];
            acc[b] += h4.x * wv[d4 * 4] + h4.y * wv[d4 * 4 + 1]
                    + h4.z * wv[d4 * 4 + 2] + h4.w * wv[d4 * 4 + 3];
        }
    }

    float* op = g1p + (size_t)blockIdx.y * BB * HH;   // [ks][b][HH]
    #pragma unroll
    for (int b = 0; b < BB; ++b) op[(size_t)b * HH + j] = acc[b];
}

// ---------------------------------------------------------------------------
// Kernel D: gemm2 with inline combine of g1p partials + bias + exact gelu
// (g1p is L2-resident; 3x redundancy across cb blocks is cheap).
// grid (3, 48) = 144 blocks.
// ---------------------------------------------------------------------------
__global__ __launch_bounds__(256) void gemm2_gelu_k(
    const float* __restrict__ g1p, const float* __restrict__ b1,
    const float* __restrict__ w2, float* __restrict__ g2p)
{
    const int cb  = blockIdx.x;
    const int ks  = blockIdx.y;
    const int k0  = ks * KL2;
    const int tid = threadIdx.x;

    __shared__ float hg[BB][KL2];
    for (int i = tid; i < BB * KL2; i += 256) {
        const int b = i / KL2, d = i - b * KL2, j = k0 + d;
        float a = b1[j];
        #pragma unroll
        for (int s = 0; s < KS1; ++s) a += g1p[((size_t)s * BB + b) * HH + j];
        hg[b][d] = 0.5f * a * (1.f + erff(a * 0.70710678118654752f));
    }
    __syncthreads();

    const int col = cb * 256 + tid;
    float wv[KL2];
    #pragma unroll
    for (int d = 0; d < KL2; ++d) wv[d] = w2[(size_t)(k0 + d) * DD + col];

    float acc[BB];
    #pragma unroll
    for (int b = 0; b < BB; ++b) acc[b] = 0.f;

    #pragma unroll
    for (int d4 = 0; d4 < KL2 / 4; ++d4) {
        #pragma unroll
        for (int b = 0; b < BB; ++b) {
            const float4 h4 = *(const float4*)&hg[b][d4 * 4];
            acc[b] += h4.x * wv[d4 * 4] + h4.y * wv[d4 * 4 + 1]
                    + h4.z * wv[d4 * 4 + 2] + h4.w * wv[d4 * 4 + 3];
        }
    }

    float* op = g2p + (size_t)ks * BB * DD;   // [ks][b][DD]
    #pragma unroll
    for (int b = 0; b < BB; ++b) op[(size_t)b * DD + col] = acc[b];
}

// ---------------------------------------------------------------------------
// Kernel E: out = pooled + b2 + sum_s g2p. 48 blocks.
// ---------------------------------------------------------------------------
__global__ __launch_bounds__(256) void comb2_fin_k(
    const float* __restrict__ g2p, const float* __restrict__ pooled_ws,
    const float* __restrict__ b2, float* __restrict__ out)
{
    const int i = blockIdx.x * 256 + threadIdx.x;   // < 12288
    const int d = i % DD;

    float a = pooled_ws[i] + b2[d];
    #pragma unroll
    for (int s = 0; s < KS2; ++s) a += g2p[(size_t)s * BB * DD + i];
    out[i] = a;
}

extern "C" void kernel_launch(void* const* d_in, const int* in_sizes, int n_in,
                              void* d_out, int out_size, void* d_ws, size_t ws_size,
                              hipStream_t stream)
{
    const float* x     = (const float*)d_in[0];
    const float* query = (const float*)d_in[1];
    const float* gamma = (const float*)d_in[2];
    const float* beta  = (const float*)d_in[3];
    const float* w1    = (const float*)d_in[4];
    const float* b1    = (const float*)d_in[5];
    const float* w2    = (const float*)d_in[6];
    const float* b2    = (const float*)d_in[7];

    float* out      = (float*)d_out;       // [16][768]
    float* attn_out = out + BB * DD;       // [16][8192] raw logits

    float* ws       = (float*)d_ws;
    float* partials = ws;                               // 16*64*772
    float* qsum     = partials + BB * CHUNKS * PSTRIDE; // 16*4*768
    float* qden     = qsum + BB * QQ * DD;              // 64
    float* pooled   = qden + 64;
    float* hln      = pooled + BB * DD;
    float* g1p      = hln + BB * DD;                    // 16*16*3072
    float* g2p      = g1p + KS1 * BB * HH;              // 48*16*768
    int*   qcnt     = (int*)(g2p + KS2 * BB * DD);

    hipMemsetAsync(qcnt, 0, sizeof(int), stream);
    attn_pool_k<<<dim3(CHUNKS, BB), 256, 0, stream>>>(x, query, attn_out, partials);
    qreduce_ln_k<<<dim3(12, BB), 256, 0, stream>>>(partials, qsum, qden, gamma,
                                                   beta, pooled, hln, qcnt);
    gemm1_part_k<<<dim3(HH / 256, KS1), 256, 0, stream>>>(hln, w1, g1p);
    gemm2_gelu_k<<<dim3(DD / 256, KS2), 256, 0, stream>>>(g1p, b1, w2, g2p);
    comb2_fin_k<<<dim3(BB * DD / 256), 256, 0, stream>>>(g2p, pooled, b2, out);
}

// Round 8
// 109.826 us; speedup vs baseline: 1.1911x; 1.1911x over previous
//
#include <hip/hip_runtime.h>
#include <hip/hip_bf16.h>
#include <math.h>

#define BB 16
#define NN 8192
#define DD 768
#define HH 3072
#define EPSV 1e-6f
#define DSQRT 0.03608439182435161f   // 768^-0.5

#define CHUNKS 64
#define ROWS_PER_BLOCK (NN / CHUNKS)              // 128
#define NWAVES 4
#define ROWS_PER_WAVE (ROWS_PER_BLOCK / NWAVES)   // 32
#define RB 4                                      // rows batched per iteration
#define PSTRIDE 772                               // 768 pooled + 1 denom
#define QQ 4                                      // chunk quarters

#define KS1 16
#define KL1 (DD / KS1)    // 48
#define KS2 48
#define KL2 (HH / KS2)    // 64

// ---------------------------------------------------------------------------
// Kernel A: single pass over x, RB=4 rows per iteration: 12 independent
// float4 loads in flight, 4 interleaved shuffle-reduce chains.
// ---------------------------------------------------------------------------
__global__ __launch_bounds__(256) void attn_pool_k(
    const float* __restrict__ x, const float* __restrict__ query,
    float* __restrict__ attn_out, float* __restrict__ partials)
{
    const int b     = blockIdx.y;
    const int chunk = blockIdx.x;
    const int tid   = threadIdx.x;
    const int wave  = tid >> 6;
    const int lane  = tid & 63;

    const float4* q4 = (const float4*)query;
    const float4 q0 = q4[lane];
    const float4 q1 = q4[lane + 64];
    const float4 q2 = q4[lane + 128];

    float4 p0 = make_float4(0.f, 0.f, 0.f, 0.f);
    float4 p1 = make_float4(0.f, 0.f, 0.f, 0.f);
    float4 p2 = make_float4(0.f, 0.f, 0.f, 0.f);
    float esum = 0.f;

    const int n0 = chunk * ROWS_PER_BLOCK + wave * ROWS_PER_WAVE;
    const float4* xb = (const float4*)(x + (size_t)b * NN * DD);

    for (int it = 0; it < ROWS_PER_WAVE / RB; ++it) {
        const int n = n0 + it * RB;
        float4 v[RB][3];
        #pragma unroll
        for (int r = 0; r < RB; ++r) {
            const float4* xr = xb + (size_t)(n + r) * (DD / 4);
            v[r][0] = xr[lane];
            v[r][1] = xr[lane + 64];
            v[r][2] = xr[lane + 128];
        }

        float s[RB];
        #pragma unroll
        for (int r = 0; r < RB; ++r) {
            float a;
            a  = v[r][0].x * q0.x + v[r][0].y * q0.y + v[r][0].z * q0.z + v[r][0].w * q0.w;
            a += v[r][1].x * q1.x + v[r][1].y * q1.y + v[r][1].z * q1.z + v[r][1].w * q1.w;
            a += v[r][2].x * q2.x + v[r][2].y * q2.y + v[r][2].z * q2.z + v[r][2].w * q2.w;
            s[r] = a;
        }

        // 4 interleaved butterflies (DS latency amortized across rows)
        #pragma unroll
        for (int k = 0; k < 6; ++k) {
            const int off = 32 >> k;
            #pragma unroll
            for (int r = 0; r < RB; ++r) s[r] += __shfl_xor(s[r], off);
        }

        if (lane == 0)
            *(float4*)&attn_out[(size_t)b * NN + n] = make_float4(s[0], s[1], s[2], s[3]);

        float e[RB];
        #pragma unroll
        for (int r = 0; r < RB; ++r) { e[r] = expf(s[r] * DSQRT); esum += e[r]; }

        #pragma unroll
        for (int r = 0; r < RB; ++r) {
            p0.x += e[r] * v[r][0].x; p0.y += e[r] * v[r][0].y;
            p0.z += e[r] * v[r][0].z; p0.w += e[r] * v[r][0].w;
            p1.x += e[r] * v[r][1].x; p1.y += e[r] * v[r][1].y;
            p1.z += e[r] * v[r][1].z; p1.w += e[r] * v[r][1].w;
            p2.x += e[r] * v[r][2].x; p2.y += e[r] * v[r][2].y;
            p2.z += e[r] * v[r][2].z; p2.w += e[r] * v[r][2].w;
        }
    }

    __shared__ float lds[NWAVES][PSTRIDE];
    float* my = lds[wave];
    *(float4*)&my[lane * 4]       = p0;
    *(float4*)&my[256 + lane * 4] = p1;
    *(float4*)&my[512 + lane * 4] = p2;
    if (lane == 0) my[768] = esum;
    __syncthreads();

    float* outp = partials + (size_t)(b * CHUNKS + chunk) * PSTRIDE;
    #pragma unroll
    for (int k = 0; k < 3; ++k) {
        const int idx = tid + k * 256;
        outp[idx] = lds[0][idx] + lds[1][idx] + lds[2][idx] + lds[3][idx];
    }
    if (tid == 0) outp[768] = lds[0][768] + lds[1][768] + lds[2][768] + lds[3][768];
}

// ---------------------------------------------------------------------------
// Kernel B0: wide quarter-reduce of partials. grid (12, 16) = 192 blocks.
// ---------------------------------------------------------------------------
__global__ __launch_bounds__(256) void qreduce_k(
    const float* __restrict__ partials, float* __restrict__ qsum,
    float* __restrict__ qden)
{
    const int slice = blockIdx.x % 3;
    const int q     = blockIdx.x / 3;
    const int b     = blockIdx.y;
    const int tid   = threadIdx.x;
    const float* pb = partials + (size_t)b * CHUNKS * PSTRIDE;

    const int col = slice * 256 + tid;
    float s = 0.f;
    #pragma unroll
    for (int c = 0; c < CHUNKS / QQ; ++c)
        s += pb[(q * (CHUNKS / QQ) + c) * PSTRIDE + col];
    qsum[(size_t)(b * QQ + q) * DD + col] = s;

    if (slice == 0 && tid < CHUNKS / QQ) {   // 16 lanes, parallel denom reduce
        float dn = pb[(q * (CHUNKS / QQ) + tid) * PSTRIDE + 768];
        #pragma unroll
        for (int off = 8; off > 0; off >>= 1) dn += __shfl_xor(dn, off, 16);
        if (tid == 0) qden[b * QQ + q] = dn;
    }
}

// ---------------------------------------------------------------------------
// Kernel B1: final reduce (196 KB) + softmax-normalize + LayerNorm.
// 16 blocks x 768 threads.
// ---------------------------------------------------------------------------
__global__ __launch_bounds__(768) void reduce_ln_k(
    const float* __restrict__ qsum, const float* __restrict__ qden,
    const float* __restrict__ gamma, const float* __restrict__ beta,
    float* __restrict__ pooled_ws, float* __restrict__ hln_ws)
{
    const int b = blockIdx.x, tid = threadIdx.x;   // tid < 768

    float v = 0.f;
    #pragma unroll
    for (int q = 0; q < QQ; ++q) v += qsum[(size_t)(b * QQ + q) * DD + tid];

    const float den = qden[b * QQ] + qden[b * QQ + 1]
                    + qden[b * QQ + 2] + qden[b * QQ + 3];
    v *= (1.f / den);

    __shared__ float red[768];
    red[tid] = v;
    __syncthreads();
    if (tid < 256) red[tid] += red[tid + 256] + red[tid + 512];
    __syncthreads();
    for (int s = 128; s > 0; s >>= 1) {
        if (tid < s) red[tid] += red[tid + s];
        __syncthreads();
    }
    const float mu = red[0] * (1.f / 768.f);
    __syncthreads();

    const float dmu = v - mu;
    red[tid] = dmu * dmu;
    __syncthreads();
    if (tid < 256) red[tid] += red[tid + 256] + red[tid + 512];
    __syncthreads();
    for (int s = 128; s > 0; s >>= 1) {
        if (tid < s) red[tid] += red[tid + s];
        __syncthreads();
    }
    const float var = red[0] * (1.f / 768.f);
    const float rstd = rsqrtf(var + EPSV);

    pooled_ws[(size_t)b * DD + tid] = v;
    hln_ws[(size_t)b * DD + tid] = (v - mu) * rstd * gamma[tid] + beta[tid];
}

// ---------------------------------------------------------------------------
// Kernel C: B-major K-split partial of hln @ w1. grid (12, 16) = 192 blocks.
// ---------------------------------------------------------------------------
__global__ __launch_bounds__(256) void gemm1_part_k(
    const float* __restrict__ hln_ws, const float* __restrict__ w1,
    float* __restrict__ g1p)
{
    const int j  = blockIdx.x * 256 + threadIdx.x;  // hidden column
    const int k0 = blockIdx.y * KL1;                // K offset

    __shared__ float hl[BB][KL1];
    for (int i = threadIdx.x; i < BB * KL1; i += 256) {
        const int b = i / KL1, d = i - b * KL1;
        hl[b][d] = hln_ws[(size_t)b * DD + k0 + d];
    }
    __syncthreads();

    float wv[KL1];
    #pragma unroll
    for (int d = 0; d < KL1; ++d) wv[d] = w1[(size_t)(k0 + d) * HH + j];

    float acc[BB];
    #pragma unroll
    for (int b = 0; b < BB; ++b) acc[b] = 0.f;

    #pragma unroll
    for (int d4 = 0; d4 < KL1 / 4; ++d4) {
        #pragma unroll
        for (int b = 0; b < BB; ++b) {
            const float4 h4 = *(const float4*)&hl[b][d4 * 4];
            acc[b] += h4.x * wv[d4 * 4] + h4.y * wv[d4 * 4 + 1]
                    + h4.z * wv[d4 * 4 + 2] + h4.w * wv[d4 * 4 + 3];
        }
    }

    float* op = g1p + (size_t)blockIdx.y * BB * HH;   // [ks][b][HH]
    #pragma unroll
    for (int b = 0; b < BB; ++b) op[(size_t)b * HH + j] = acc[b];
}

// ---------------------------------------------------------------------------
// Kernel D: combine K-split partials + bias + exact gelu. 192 blocks.
// ---------------------------------------------------------------------------
__global__ __launch_bounds__(256) void comb1_gelu_k(
    const float* __restrict__ g1p, const float* __restrict__ b1,
    float* __restrict__ h1_ws)
{
    const int i = blockIdx.x * 256 + threadIdx.x;   // < 16*3072
    const int j = i % HH;

    float a = b1[j];
    #pragma unroll
    for (int s = 0; s < KS1; ++s) a += g1p[(size_t)s * BB * HH + i];
    h1_ws[i] = 0.5f * a * (1.f + erff(a * 0.70710678118654752f));
}

// ---------------------------------------------------------------------------
// Kernel E: B-major K-split partial of h1 @ w2. grid (3, 48) = 144 blocks.
// ---------------------------------------------------------------------------
__global__ __launch_bounds__(256) void gemm2_part_k(
    const float* __restrict__ h1_ws, const float* __restrict__ w2,
    float* __restrict__ g2p)
{
    const int col = blockIdx.x * 256 + threadIdx.x;  // out column
    const int k0  = blockIdx.y * KL2;                // K offset

    __shared__ float hg[BB][KL2];
    for (int i = threadIdx.x; i < BB * KL2; i += 256) {
        const int b = i / KL2, d = i - b * KL2;
        hg[b][d] = h1_ws[(size_t)b * HH + k0 + d];
    }
    __syncthreads();

    float wv[KL2];
    #pragma unroll
    for (int d = 0; d < KL2; ++d) wv[d] = w2[(size_t)(k0 + d) * DD + col];

    float acc[BB];
    #pragma unroll
    for (int b = 0; b < BB; ++b) acc[b] = 0.f;

    #pragma unroll
    for (int d4 = 0; d4 < KL2 / 4; ++d4) {
        #pragma unroll
        for (int b = 0; b < BB; ++b) {
            const float4 h4 = *(const float4*)&hg[b][d4 * 4];
            acc[b] += h4.x * wv[d4 * 4] + h4.y * wv[d4 * 4 + 1]
                    + h4.z * wv[d4 * 4 + 2] + h4.w * wv[d4 * 4 + 3];
        }
    }

    float* op = g2p + (size_t)blockIdx.y * BB * DD;   // [ks][b][DD]
    #pragma unroll
    for (int b = 0; b < BB; ++b) op[(size_t)b * DD + col] = acc[b];
}

// ---------------------------------------------------------------------------
// Kernel F: out = pooled + b2 + sum_s g2p. 48 blocks.
// ---------------------------------------------------------------------------
__global__ __launch_bounds__(256) void comb2_fin_k(
    const float* __restrict__ g2p, const float* __restrict__ pooled_ws,
    const float* __restrict__ b2, float* __restrict__ out)
{
    const int i = blockIdx.x * 256 + threadIdx.x;   // < 12288
    const int d = i % DD;

    float a = pooled_ws[i] + b2[d];
    #pragma unroll
    for (int s = 0; s < KS2; ++s) a += g2p[(size_t)s * BB * DD + i];
    out[i] = a;
}

extern "C" void kernel_launch(void* const* d_in, const int* in_sizes, int n_in,
                              void* d_out, int out_size, void* d_ws, size_t ws_size,
                              hipStream_t stream)
{
    const float* x     = (const float*)d_in[0];
    const float* query = (const float*)d_in[1];
    const float* gamma = (const float*)d_in[2];
    const float* beta  = (const float*)d_in[3];
    const float* w1    = (const float*)d_in[4];
    const float* b1    = (const float*)d_in[5];
    const float* w2    = (const float*)d_in[6];
    const float* b2    = (const float*)d_in[7];

    float* out      = (float*)d_out;       // [16][768]
    float* attn_out = out + BB * DD;       // [16][8192] raw logits

    float* ws       = (float*)d_ws;
    float* partials = ws;                               // 16*64*772
    float* qsum     = partials + BB * CHUNKS * PSTRIDE; // 16*4*768
    float* qden     = qsum + BB * QQ * DD;              // 64
    float* pooled   = qden + 64;
    float* hln      = pooled + BB * DD;
    float* h1       = hln + BB * DD;                    // 16*3072
    float* g1p      = h1 + BB * HH;                     // 16*16*3072
    float* g2p      = g1p + KS1 * BB * HH;              // 48*16*768

    attn_pool_k<<<dim3(CHUNKS, BB), 256, 0, stream>>>(x, query, attn_out, partials);
    qreduce_k<<<dim3(12, BB), 256, 0, stream>>>(partials, qsum, qden);
    reduce_ln_k<<<dim3(BB), 768, 0, stream>>>(qsum, qden, gamma, beta, pooled, hln);
    gemm1_part_k<<<dim3(HH / 256, KS1), 256, 0, stream>>>(hln, w1, g1p);
    comb1_gelu_k<<<dim3(BB * HH / 256), 256, 0, stream>>>(g1p, b1, h1);
    gemm2_part_k<<<dim3(DD / 256, KS2), 256, 0, stream>>>(h1, w2, g2p);
    comb2_fin_k<<<dim3(BB * DD / 256), 256, 0, stream>>>(g2p, pooled, b2, out);
}

// Round 9
// 106.233 us; speedup vs baseline: 1.2313x; 1.0338x over previous
//
#include <hip/hip_runtime.h>
#include <hip/hip_bf16.h>
#include <math.h>

#define BB 16
#define NN 8192
#define DD 768
#define HH 3072
#define EPSV 1e-6f
#define DSQRT 0.03608439182435161f   // 768^-0.5

#define CHUNKS 64
#define ROWS_PER_BLOCK (NN / CHUNKS)              // 128
#define NWAVES 4
#define ROWS_PER_WAVE (ROWS_PER_BLOCK / NWAVES)   // 32
#define PSTRIDE 772                               // 768 pooled + 1 denom
#define QQ 4                                      // chunk quarters

#define KS1 16
#define KL1 (DD / KS1)    // 48
#define KS2 48
#define KL2 (HH / KS2)    // 64

typedef __attribute__((ext_vector_type(4))) float f32x4;

// ---------------------------------------------------------------------------
// Kernel A: single pass over x (R6 structure), with NONTEMPORAL loads on x
// (streamed once, zero reuse -> bypass cache allocation) and nt stores for
// the never-re-read logits.
// ---------------------------------------------------------------------------
__global__ __launch_bounds__(256) void attn_pool_k(
    const float* __restrict__ x, const float* __restrict__ query,
    float* __restrict__ attn_out, float* __restrict__ partials)
{
    const int b     = blockIdx.y;
    const int chunk = blockIdx.x;
    const int tid   = threadIdx.x;
    const int wave  = tid >> 6;
    const int lane  = tid & 63;

    const f32x4* q4 = (const f32x4*)query;
    const f32x4 q0 = q4[lane];
    const f32x4 q1 = q4[lane + 64];
    const f32x4 q2 = q4[lane + 128];

    f32x4 p0 = (f32x4)0.f;
    f32x4 p1 = (f32x4)0.f;
    f32x4 p2 = (f32x4)0.f;
    float esum = 0.f;

    const int n0 = chunk * ROWS_PER_BLOCK + wave * ROWS_PER_WAVE;
    const f32x4* xb = (const f32x4*)(x + (size_t)b * NN * DD);

    #pragma unroll 2
    for (int r = 0; r < ROWS_PER_WAVE; ++r) {
        const int n = n0 + r;
        const f32x4* xr = xb + (size_t)n * (DD / 4);
        const f32x4 v0 = __builtin_nontemporal_load(&xr[lane]);
        const f32x4 v1 = __builtin_nontemporal_load(&xr[lane + 64]);
        const f32x4 v2 = __builtin_nontemporal_load(&xr[lane + 128]);

        const f32x4 t = v0 * q0 + v1 * q1 + v2 * q2;
        float s = t[0] + t[1] + t[2] + t[3];
        #pragma unroll
        for (int off = 32; off > 0; off >>= 1) s += __shfl_xor(s, off);

        if (lane == 0)
            __builtin_nontemporal_store(s, &attn_out[(size_t)b * NN + n]);

        const float e = expf(s * DSQRT);
        esum += e;
        p0 += v0 * e;
        p1 += v1 * e;
        p2 += v2 * e;
    }

    __shared__ float lds[NWAVES][PSTRIDE];
    float* my = lds[wave];
    *(f32x4*)&my[lane * 4]       = p0;
    *(f32x4*)&my[256 + lane * 4] = p1;
    *(f32x4*)&my[512 + lane * 4] = p2;
    if (lane == 0) my[768] = esum;
    __syncthreads();

    float* outp = partials + (size_t)(b * CHUNKS + chunk) * PSTRIDE;
    #pragma unroll
    for (int k = 0; k < 3; ++k) {
        const int idx = tid + k * 256;
        outp[idx] = lds[0][idx] + lds[1][idx] + lds[2][idx] + lds[3][idx];
    }
    if (tid == 0) outp[768] = lds[0][768] + lds[1][768] + lds[2][768] + lds[3][768];
}

// ---------------------------------------------------------------------------
// Kernel B0: wide quarter-reduce of partials. grid (12, 16) = 192 blocks.
// ---------------------------------------------------------------------------
__global__ __launch_bounds__(256) void qreduce_k(
    const float* __restrict__ partials, float* __restrict__ qsum,
    float* __restrict__ qden)
{
    const int slice = blockIdx.x % 3;
    const int q     = blockIdx.x / 3;
    const int b     = blockIdx.y;
    const int tid   = threadIdx.x;
    const float* pb = partials + (size_t)b * CHUNKS * PSTRIDE;

    const int col = slice * 256 + tid;
    float s = 0.f;
    #pragma unroll
    for (int c = 0; c < CHUNKS / QQ; ++c)
        s += pb[(q * (CHUNKS / QQ) + c) * PSTRIDE + col];
    qsum[(size_t)(b * QQ + q) * DD + col] = s;

    if (slice == 0 && tid < CHUNKS / QQ) {   // 16 lanes, parallel denom reduce
        float dn = pb[(q * (CHUNKS / QQ) + tid) * PSTRIDE + 768];
        #pragma unroll
        for (int off = 8; off > 0; off >>= 1) dn += __shfl_xor(dn, off, 16);
        if (tid == 0) qden[b * QQ + q] = dn;
    }
}

// ---------------------------------------------------------------------------
// Kernel B1: final reduce (196 KB) + softmax-normalize + LayerNorm.
// 16 blocks x 768 threads.
// ---------------------------------------------------------------------------
__global__ __launch_bounds__(768) void reduce_ln_k(
    const float* __restrict__ qsum, const float* __restrict__ qden,
    const float* __restrict__ gamma, const float* __restrict__ beta,
    float* __restrict__ pooled_ws, float* __restrict__ hln_ws)
{
    const int b = blockIdx.x, tid = threadIdx.x;   // tid < 768

    float v = 0.f;
    #pragma unroll
    for (int q = 0; q < QQ; ++q) v += qsum[(size_t)(b * QQ + q) * DD + tid];

    const float den = qden[b * QQ] + qden[b * QQ + 1]
                    + qden[b * QQ + 2] + qden[b * QQ + 3];
    v *= (1.f / den);

    __shared__ float red[768];
    red[tid] = v;
    __syncthreads();
    if (tid < 256) red[tid] += red[tid + 256] + red[tid + 512];
    __syncthreads();
    for (int s = 128; s > 0; s >>= 1) {
        if (tid < s) red[tid] += red[tid + s];
        __syncthreads();
    }
    const float mu = red[0] * (1.f / 768.f);
    __syncthreads();

    const float dmu = v - mu;
    red[tid] = dmu * dmu;
    __syncthreads();
    if (tid < 256) red[tid] += red[tid + 256] + red[tid + 512];
    __syncthreads();
    for (int s = 128; s > 0; s >>= 1) {
        if (tid < s) red[tid] += red[tid + s];
        __syncthreads();
    }
    const float var = red[0] * (1.f / 768.f);
    const float rstd = rsqrtf(var + EPSV);

    pooled_ws[(size_t)b * DD + tid] = v;
    hln_ws[(size_t)b * DD + tid] = (v - mu) * rstd * gamma[tid] + beta[tid];
}

// ---------------------------------------------------------------------------
// Kernel C: B-major K-split partial of hln @ w1. grid (12, 16) = 192 blocks.
// ---------------------------------------------------------------------------
__global__ __launch_bounds__(256) void gemm1_part_k(
    const float* __restrict__ hln_ws, const float* __restrict__ w1,
    float* __restrict__ g1p)
{
    const int j  = blockIdx.x * 256 + threadIdx.x;  // hidden column
    const int k0 = blockIdx.y * KL1;                // K offset

    __shared__ float hl[BB][KL1];
    for (int i = threadIdx.x; i < BB * KL1; i += 256) {
        const int b = i / KL1, d = i - b * KL1;
        hl[b][d] = hln_ws[(size_t)b * DD + k0 + d];
    }
    __syncthreads();

    float wv[KL1];
    #pragma unroll
    for (int d = 0; d < KL1; ++d) wv[d] = w1[(size_t)(k0 + d) * HH + j];

    float acc[BB];
    #pragma unroll
    for (int b = 0; b < BB; ++b) acc[b] = 0.f;

    #pragma unroll
    for (int d4 = 0; d4 < KL1 / 4; ++d4) {
        #pragma unroll
        for (int b = 0; b < BB; ++b) {
            const float4 h4 = *(const float4*)&hl[b][d4 * 4];
            acc[b] += h4.x * wv[d4 * 4] + h4.y * wv[d4 * 4 + 1]
                    + h4.z * wv[d4 * 4 + 2] + h4.w * wv[d4 * 4 + 3];
        }
    }

    float* op = g1p + (size_t)blockIdx.y * BB * HH;   // [ks][b][HH]
    #pragma unroll
    for (int b = 0; b < BB; ++b) op[(size_t)b * HH + j] = acc[b];
}

// ---------------------------------------------------------------------------
// Kernel D: combine K-split partials + bias + exact gelu. 192 blocks.
// ---------------------------------------------------------------------------
__global__ __launch_bounds__(256) void comb1_gelu_k(
    const float* __restrict__ g1p, const float* __restrict__ b1,
    float* __restrict__ h1_ws)
{
    const int i = blockIdx.x * 256 + threadIdx.x;   // < 16*3072
    const int j = i % HH;

    float a = b1[j];
    #pragma unroll
    for (int s = 0; s < KS1; ++s) a += g1p[(size_t)s * BB * HH + i];
    h1_ws[i] = 0.5f * a * (1.f + erff(a * 0.70710678118654752f));
}

// ---------------------------------------------------------------------------
// Kernel E: B-major K-split partial of h1 @ w2. grid (3, 48) = 144 blocks.
// ---------------------------------------------------------------------------
__global__ __launch_bounds__(256) void gemm2_part_k(
    const float* __restrict__ h1_ws, const float* __restrict__ w2,
    float* __restrict__ g2p)
{
    const int col = blockIdx.x * 256 + threadIdx.x;  // out column
    const int k0  = blockIdx.y * KL2;                // K offset

    __shared__ float hg[BB][KL2];
    for (int i = threadIdx.x; i < BB * KL2; i += 256) {
        const int b = i / KL2, d = i - b * KL2;
        hg[b][d] = h1_ws[(size_t)b * HH + k0 + d];
    }
    __syncthreads();

    float wv[KL2];
    #pragma unroll
    for (int d = 0; d < KL2; ++d) wv[d] = w2[(size_t)(k0 + d) * DD + col];

    float acc[BB];
    #pragma unroll
    for (int b = 0; b < BB; ++b) acc[b] = 0.f;

    #pragma unroll
    for (int d4 = 0; d4 < KL2 / 4; ++d4) {
        #pragma unroll
        for (int b = 0; b < BB; ++b) {
            const float4 h4 = *(const float4*)&hg[b][d4 * 4];
            acc[b] += h4.x * wv[d4 * 4] + h4.y * wv[d4 * 4 + 1]
                    + h4.z * wv[d4 * 4 + 2] + h4.w * wv[d4 * 4 + 3];
        }
    }

    float* op = g2p + (size_t)blockIdx.y * BB * DD;   // [ks][b][DD]
    #pragma unroll
    for (int b = 0; b < BB; ++b) op[(size_t)b * DD + col] = acc[b];
}

// ---------------------------------------------------------------------------
// Kernel F: out = pooled + b2 + sum_s g2p. 48 blocks.
// ---------------------------------------------------------------------------
__global__ __launch_bounds__(256) void comb2_fin_k(
    const float* __restrict__ g2p, const float* __restrict__ pooled_ws,
    const float* __restrict__ b2, float* __restrict__ out)
{
    const int i = blockIdx.x * 256 + threadIdx.x;   // < 12288
    const int d = i % DD;

    float a = pooled_ws[i] + b2[d];
    #pragma unroll
    for (int s = 0; s < KS2; ++s) a += g2p[(size_t)s * BB * DD + i];
    out[i] = a;
}

extern "C" void kernel_launch(void* const* d_in, const int* in_sizes, int n_in,
                              void* d_out, int out_size, void* d_ws, size_t ws_size,
                              hipStream_t stream)
{
    const float* x     = (const float*)d_in[0];
    const float* query = (const float*)d_in[1];
    const float* gamma = (const float*)d_in[2];
    const float* beta  = (const float*)d_in[3];
    const float* w1    = (const float*)d_in[4];
    const float* b1    = (const float*)d_in[5];
    const float* w2    = (const float*)d_in[6];
    const float* b2    = (const float*)d_in[7];

    float* out      = (float*)d_out;       // [16][768]
    float* attn_out = out + BB * DD;       // [16][8192] raw logits

    float* ws       = (float*)d_ws;
    float* partials = ws;                               // 16*64*772
    float* qsum     = partials + BB * CHUNKS * PSTRIDE; // 16*4*768
    float* qden     = qsum + BB * QQ * DD;              // 64
    float* pooled   = qden + 64;
    float* hln      = pooled + BB * DD;
    float* h1       = hln + BB * DD;                    // 16*3072
    float* g1p      = h1 + BB * HH;                     // 16*16*3072
    float* g2p      = g1p + KS1 * BB * HH;              // 48*16*768

    attn_pool_k<<<dim3(CHUNKS, BB), 256, 0, stream>>>(x, query, attn_out, partials);
    qreduce_k<<<dim3(12, BB), 256, 0, stream>>>(partials, qsum, qden);
    reduce_ln_k<<<dim3(BB), 768, 0, stream>>>(qsum, qden, gamma, beta, pooled, hln);
    gemm1_part_k<<<dim3(HH / 256, KS1), 256, 0, stream>>>(hln, w1, g1p);
    comb1_gelu_k<<<dim3(BB * HH / 256), 256, 0, stream>>>(g1p, b1, h1);
    gemm2_part_k<<<dim3(DD / 256, KS2), 256, 0, stream>>>(h1, w2, g2p);
    comb2_fin_k<<<dim3(BB * DD / 256), 256, 0, stream>>>(g2p, pooled, b2, out);
}